// Round 2
// baseline (2188.977 us; speedup 1.0000x reference)
//
#include <hip/hip_runtime.h>
#include <math.h>

#define N_NODES 100000
#define E_EDGES 1600000
#define F_IN 32
#define HID 16
#define NC 10

// ---------------- Kernel 1: per-node projections for layer 1 ----------------
// y[n][0:16] = x@W1[0]; y[n][16:32] = x@W1[1]; r1[n][0:16] = x@root1 + b1
__global__ __launch_bounds__(256) void node_l1(
    const float* __restrict__ x, const float* __restrict__ W1,
    const float* __restrict__ root1, const float* __restrict__ b1,
    float* __restrict__ y, float* __restrict__ r1)
{
    __shared__ float sW0[F_IN * HID], sW1[F_IN * HID], sR[F_IN * HID], sB[HID];
    for (int i = threadIdx.x; i < F_IN * HID; i += 256) {
        sW0[i] = W1[i];
        sW1[i] = W1[F_IN * HID + i];
        sR[i]  = root1[i];
    }
    if (threadIdx.x < HID) sB[threadIdx.x] = b1[threadIdx.x];
    __syncthreads();

    int n = blockIdx.x * 256 + threadIdx.x;
    if (n >= N_NODES) return;

    float xr[F_IN];
    const float4* xp = (const float4*)(x + (size_t)n * F_IN);
    #pragma unroll
    for (int i = 0; i < F_IN / 4; i++) {
        float4 t = xp[i];
        xr[i*4+0] = t.x; xr[i*4+1] = t.y; xr[i*4+2] = t.z; xr[i*4+3] = t.w;
    }

    float a0[HID], a1[HID], ar[HID];
    #pragma unroll
    for (int o = 0; o < HID; o++) { a0[o] = 0.f; a1[o] = 0.f; ar[o] = sB[o]; }
    for (int i = 0; i < F_IN; i++) {
        float xi = xr[i];
        #pragma unroll
        for (int o = 0; o < HID; o++) {
            a0[o] += xi * sW0[i * HID + o];
            a1[o] += xi * sW1[i * HID + o];
            ar[o] += xi * sR[i * HID + o];
        }
    }
    float* py = y + (size_t)n * 32;
    float* pr = r1 + (size_t)n * HID;
    #pragma unroll
    for (int o = 0; o < HID; o++) { py[o] = a0[o]; py[16 + o] = a1[o]; pr[o] = ar[o]; }
}

// ---------------- Kernel 2: edge gather/scatter for layer 1 ----------------
// 16 lanes per edge; lane o handles output component o.
// agg1 is COMPONENT-MAJOR: agg1[o*N + dst] -> 16 atomics hit 16 distinct lines.
__global__ __launch_bounds__(256) void edge_l1(
    const int* __restrict__ ei, const float* __restrict__ ea,
    const float* __restrict__ y,
    float* __restrict__ agg1, float* __restrict__ deg)
{
    int idx = blockIdx.x * 256 + threadIdx.x;
    int e = idx >> 4, o = idx & 15;
    if (e >= E_EDGES) return;
    int src = ei[e];
    int dst = ei[E_EDGES + e];
    float v = ea[e];                 // K=2: basis = [1-v, v]
    float a = y[(size_t)src * 32 + o];
    float b = y[(size_t)src * 32 + 16 + o];
    float m = fmaf(v, b - a, a);     // a*(1-v) + b*v
    atomicAdd(&agg1[(size_t)o * N_NODES + dst], m);
    if (o == 0) atomicAdd(&deg[dst], 1.0f);
}

// -------- Kernel 3: finish layer 1 (mean + root + elu), prep layer 2 --------
// Reads agg1 component-major (coalesced). Writes z[n][0:10]=z0, z[n][16:26]=z1.
__global__ __launch_bounds__(256) void node_mid(
    const float* __restrict__ agg1, const float* __restrict__ deg,
    const float* __restrict__ r1,
    const float* __restrict__ W2, const float* __restrict__ root2,
    const float* __restrict__ b2,
    float* __restrict__ z, float* __restrict__ r2)
{
    __shared__ float sW0[HID * NC], sW1[HID * NC], sR[HID * NC], sB[NC];
    for (int i = threadIdx.x; i < HID * NC; i += 256) {
        sW0[i] = W2[i];
        sW1[i] = W2[HID * NC + i];
        sR[i]  = root2[i];
    }
    if (threadIdx.x < NC) sB[threadIdx.x] = b2[threadIdx.x];
    __syncthreads();

    int n = blockIdx.x * 256 + threadIdx.x;
    if (n >= N_NODES) return;

    float inv = 1.0f / fmaxf(deg[n], 1.0f);
    float h[HID];
    #pragma unroll
    for (int o = 0; o < HID; o++) {
        float hv = agg1[(size_t)o * N_NODES + n] * inv + r1[(size_t)n * HID + o];
        h[o] = hv > 0.0f ? hv : expm1f(hv);   // elu
    }
    float a0[NC], a1[NC], ar[NC];
    #pragma unroll
    for (int c = 0; c < NC; c++) { a0[c] = 0.f; a1[c] = 0.f; ar[c] = sB[c]; }
    for (int i = 0; i < HID; i++) {
        float hi = h[i];
        #pragma unroll
        for (int c = 0; c < NC; c++) {
            a0[c] += hi * sW0[i * NC + c];
            a1[c] += hi * sW1[i * NC + c];
            ar[c] += hi * sR[i * NC + c];
        }
    }
    float* pz = z + (size_t)n * 32;
    float* pr = r2 + (size_t)n * NC;
    #pragma unroll
    for (int c = 0; c < NC; c++) { pz[c] = a0[c]; pz[16 + c] = a1[c]; pr[c] = ar[c]; }
}

// ---------------- Kernel 4: edge gather/scatter for layer 2 ----------------
// agg2 component-major: agg2[c*N + dst].
__global__ __launch_bounds__(256) void edge_l2(
    const int* __restrict__ ei, const float* __restrict__ ea,
    const float* __restrict__ z, float* __restrict__ agg2)
{
    int idx = blockIdx.x * 256 + threadIdx.x;
    int e = idx >> 4, o = idx & 15;
    if (e >= E_EDGES || o >= NC) return;
    int src = ei[e];
    int dst = ei[E_EDGES + e];
    float v = ea[e];
    float a = z[(size_t)src * 32 + o];
    float b = z[(size_t)src * 32 + 16 + o];
    float m = fmaf(v, b - a, a);
    atomicAdd(&agg2[(size_t)o * N_NODES + dst], m);
}

// ---------------- Kernel 5: mean + root + log_softmax -> out ----------------
__global__ __launch_bounds__(256) void node_out(
    const float* __restrict__ agg2, const float* __restrict__ deg,
    const float* __restrict__ r2, float* __restrict__ out)
{
    int n = blockIdx.x * 256 + threadIdx.x;
    if (n >= N_NODES) return;
    float inv = 1.0f / fmaxf(deg[n], 1.0f);
    float vv[NC];
    float mx = -1e30f;
    #pragma unroll
    for (int c = 0; c < NC; c++) {
        vv[c] = agg2[(size_t)c * N_NODES + n] * inv + r2[(size_t)n * NC + c];
        mx = fmaxf(mx, vv[c]);
    }
    float s = 0.f;
    #pragma unroll
    for (int c = 0; c < NC; c++) s += expf(vv[c] - mx);
    float ls = logf(s);
    float* po = out + (size_t)n * NC;
    #pragma unroll
    for (int c = 0; c < NC; c++) po[c] = vv[c] - mx - ls;
}

extern "C" void kernel_launch(void* const* d_in, const int* in_sizes, int n_in,
                              void* d_out, int out_size, void* d_ws, size_t ws_size,
                              hipStream_t stream) {
    const float* x     = (const float*)d_in[0];
    const int*   ei    = (const int*)d_in[1];     // [2,E] src row then dst row
    const float* ea    = (const float*)d_in[2];   // [E,1]
    const float* W1    = (const float*)d_in[3];   // [2,32,16]
    const float* root1 = (const float*)d_in[4];   // [32,16]
    const float* b1    = (const float*)d_in[5];   // [16]
    const float* W2    = (const float*)d_in[6];   // [2,16,10]
    const float* root2 = (const float*)d_in[7];   // [16,10]
    const float* b2    = (const float*)d_in[8];   // [10]
    float* out = (float*)d_out;

    // Workspace layout (floats):
    float* ws = (float*)d_ws;
    size_t off = 0;
    float* y    = ws + off; off += (size_t)N_NODES * 32;   // y0|y1 interleaved
    float* r1   = ws + off; off += (size_t)N_NODES * HID;
    float* z    = ws + off; off += (size_t)N_NODES * 32;   // z0|z1 (padded to 16)
    float* r2   = ws + off; off += (size_t)N_NODES * NC;
    // zeroed region: agg1 | deg | agg2 (contiguous, single memset)
    float* agg1 = ws + off; off += (size_t)N_NODES * HID;  // component-major [16][N]
    float* deg  = ws + off; off += (size_t)N_NODES;
    float* agg2 = ws + off; off += (size_t)N_NODES * NC;   // component-major [10][N]

    size_t zero_bytes = (size_t)N_NODES * (HID + 1 + NC) * sizeof(float);
    hipMemsetAsync(agg1, 0, zero_bytes, stream);

    int nodeGrid = (N_NODES + 255) / 256;
    int edgeGrid = ((E_EDGES * 16) + 255) / 256;

    node_l1<<<nodeGrid, 256, 0, stream>>>(x, W1, root1, b1, y, r1);
    edge_l1<<<edgeGrid, 256, 0, stream>>>(ei, ea, y, agg1, deg);
    node_mid<<<nodeGrid, 256, 0, stream>>>(agg1, deg, r1, W2, root2, b2, z, r2);
    edge_l2<<<edgeGrid, 256, 0, stream>>>(ei, ea, z, agg2);
    node_out<<<nodeGrid, 256, 0, stream>>>(agg2, deg, r2, out);
}

// Round 3
// 623.671 us; speedup vs baseline: 3.5098x; 3.5098x over previous
//
#include <hip/hip_runtime.h>
#include <math.h>

#define N_NODES 100000
#define E_EDGES 1600000
#define F_IN 32
#define HID 16
#define NC 10
#define SCAN_T 1024
#define CHUNK 98   // ceil(100000/1024)

// bf16 pack (RNE) of two floats into one uint: low16 = lo, high16 = hi
__device__ __forceinline__ unsigned int bf16pair(float lo, float hi) {
    unsigned int ulo = __float_as_uint(lo), uhi = __float_as_uint(hi);
    ulo += 0x7fffu + ((ulo >> 16) & 1u);
    uhi += 0x7fffu + ((uhi >> 16) & 1u);
    return (ulo >> 16) | (uhi & 0xffff0000u);
}

// ---------------- Kernel: per-node projections for layer 1 ----------------
// y[n] = 16 uints, pair o = (x@W1[0])[o] , (x@W1[1])[o] in bf16. r1 = x@root1+b1 (f32).
__global__ __launch_bounds__(256) void node_l1(
    const float* __restrict__ x, const float* __restrict__ W1,
    const float* __restrict__ root1, const float* __restrict__ b1,
    unsigned int* __restrict__ y, float* __restrict__ r1)
{
    __shared__ float sW0[F_IN * HID], sW1[F_IN * HID], sR[F_IN * HID], sB[HID];
    for (int i = threadIdx.x; i < F_IN * HID; i += 256) {
        sW0[i] = W1[i];
        sW1[i] = W1[F_IN * HID + i];
        sR[i]  = root1[i];
    }
    if (threadIdx.x < HID) sB[threadIdx.x] = b1[threadIdx.x];
    __syncthreads();

    int n = blockIdx.x * 256 + threadIdx.x;
    if (n >= N_NODES) return;

    float xr[F_IN];
    const float4* xp = (const float4*)(x + (size_t)n * F_IN);
    #pragma unroll
    for (int i = 0; i < F_IN / 4; i++) {
        float4 t = xp[i];
        xr[i*4+0] = t.x; xr[i*4+1] = t.y; xr[i*4+2] = t.z; xr[i*4+3] = t.w;
    }

    float a0[HID], a1[HID], ar[HID];
    #pragma unroll
    for (int o = 0; o < HID; o++) { a0[o] = 0.f; a1[o] = 0.f; ar[o] = sB[o]; }
    for (int i = 0; i < F_IN; i++) {
        float xi = xr[i];
        #pragma unroll
        for (int o = 0; o < HID; o++) {
            a0[o] += xi * sW0[i * HID + o];
            a1[o] += xi * sW1[i * HID + o];
            ar[o] += xi * sR[i * HID + o];
        }
    }
    unsigned int* py = y + (size_t)n * 16;
    float* pr = r1 + (size_t)n * HID;
    #pragma unroll
    for (int o = 0; o < HID; o++) {
        py[o] = bf16pair(a0[o], a1[o]);
        pr[o] = ar[o];
    }
}

// ---------------- Sort step 1: histogram over dst (also = deg) ----------------
__global__ __launch_bounds__(256) void k_hist(const int* __restrict__ ei, int* __restrict__ hist)
{
    int e = blockIdx.x * 256 + threadIdx.x;
    if (e >= E_EDGES) return;
    atomicAdd(&hist[ei[E_EDGES + e]], 1);
}

// ---------------- Sort step 2: exclusive scan (single block) ----------------
__global__ __launch_bounds__(SCAN_T) void k_scan(const int* __restrict__ hist,
                                                 int* __restrict__ start,
                                                 int* __restrict__ cursor)
{
    __shared__ int lds[SCAN_T];
    int tid = threadIdx.x;
    int base = tid * CHUNK;
    int end = base + CHUNK; if (end > N_NODES) end = N_NODES;
    int s = 0;
    for (int j = base; j < end; j++) s += hist[j];
    lds[tid] = s;
    __syncthreads();
    for (int off = 1; off < SCAN_T; off <<= 1) {
        int v = (tid >= off) ? lds[tid - off] : 0;
        __syncthreads();
        lds[tid] += v;
        __syncthreads();
    }
    int running = lds[tid] - s;   // exclusive prefix of this chunk
    for (int j = base; j < end; j++) {
        start[j] = running;
        cursor[j] = running;
        running += hist[j];
    }
    if (tid == SCAN_T - 1) start[N_NODES] = lds[tid];
}

// ---------------- Sort step 3: scatter (src, v) into dst-sorted order ----------------
__global__ __launch_bounds__(256) void k_scatter(const int* __restrict__ ei,
                                                 const float* __restrict__ ea,
                                                 int* __restrict__ cursor,
                                                 int2* __restrict__ es)
{
    int e = blockIdx.x * 256 + threadIdx.x;
    if (e >= E_EDGES) return;
    int dst = ei[E_EDGES + e];
    int pos = atomicAdd(&cursor[dst], 1);
    es[pos] = make_int2(ei[e], __float_as_int(ea[e]));
}

// ------- Aggregation layer 1: 16 lanes/node, atomic-free; fused mean+root+elu -------
// In-place: r1h holds r1 on entry, h on exit.
__global__ __launch_bounds__(256) void k_agg1(
    const int2* __restrict__ es, const int* __restrict__ start,
    const int* __restrict__ hist, const unsigned int* __restrict__ y,
    float* __restrict__ r1h)
{
    int idx = blockIdx.x * 256 + threadIdx.x;
    int n = idx >> 4, o = idx & 15;
    if (n >= N_NODES) return;
    int j0 = start[n], j1 = start[n + 1];
    float acc = 0.f;
    for (int j = j0; j < j1; j++) {
        int2 p = es[j];
        float v = __int_as_float(p.y);
        unsigned int pair = y[(size_t)p.x * 16 + o];   // one 64B line per edge (16 lanes x 4B)
        float a = __uint_as_float(pair << 16);
        float b = __uint_as_float(pair & 0xffff0000u);
        acc += fmaf(v, b - a, a);                      // a*(1-v) + b*v
    }
    float inv = 1.0f / fmaxf((float)hist[n], 1.0f);
    float hv = acc * inv + r1h[(size_t)n * HID + o];
    r1h[(size_t)n * HID + o] = hv > 0.0f ? hv : expm1f(hv);  // elu
}

// ---------------- Layer-2 projections: z (bf16 pairs, padded), r2 ----------------
__global__ __launch_bounds__(256) void node_proj2(
    const float* __restrict__ h,
    const float* __restrict__ W2, const float* __restrict__ root2,
    const float* __restrict__ b2,
    unsigned int* __restrict__ z, float* __restrict__ r2)
{
    __shared__ float sW0[HID * NC], sW1[HID * NC], sR[HID * NC], sB[NC];
    for (int i = threadIdx.x; i < HID * NC; i += 256) {
        sW0[i] = W2[i];
        sW1[i] = W2[HID * NC + i];
        sR[i]  = root2[i];
    }
    if (threadIdx.x < NC) sB[threadIdx.x] = b2[threadIdx.x];
    __syncthreads();

    int n = blockIdx.x * 256 + threadIdx.x;
    if (n >= N_NODES) return;

    float hr[HID];
    const float4* hp = (const float4*)(h + (size_t)n * HID);
    #pragma unroll
    for (int i = 0; i < HID / 4; i++) {
        float4 t = hp[i];
        hr[i*4+0] = t.x; hr[i*4+1] = t.y; hr[i*4+2] = t.z; hr[i*4+3] = t.w;
    }
    float a0[NC], a1[NC], ar[NC];
    #pragma unroll
    for (int c = 0; c < NC; c++) { a0[c] = 0.f; a1[c] = 0.f; ar[c] = sB[c]; }
    for (int i = 0; i < HID; i++) {
        float hi = hr[i];
        #pragma unroll
        for (int c = 0; c < NC; c++) {
            a0[c] += hi * sW0[i * NC + c];
            a1[c] += hi * sW1[i * NC + c];
            ar[c] += hi * sR[i * NC + c];
        }
    }
    unsigned int* pz = z + (size_t)n * 16;
    float* pr = r2 + (size_t)n * NC;
    #pragma unroll
    for (int c = 0; c < NC; c++) {
        pz[c] = bf16pair(a0[c], a1[c]);
        pr[c] = ar[c];
    }
    #pragma unroll
    for (int c = NC; c < 16; c++) pz[c] = 0u;   // keep lanes 10..15 benign
}

// -- Aggregation layer 2: 16 lanes/node; fused mean+root+log_softmax (shfl, width 16) --
__global__ __launch_bounds__(256) void k_agg2(
    const int2* __restrict__ es, const int* __restrict__ start,
    const int* __restrict__ hist, const unsigned int* __restrict__ z,
    const float* __restrict__ r2, float* __restrict__ out)
{
    int idx = blockIdx.x * 256 + threadIdx.x;
    int n = idx >> 4, o = idx & 15;
    if (n >= N_NODES) return;
    int j0 = start[n], j1 = start[n + 1];
    float acc = 0.f;
    for (int j = j0; j < j1; j++) {
        int2 p = es[j];
        float v = __int_as_float(p.y);
        unsigned int pair = z[(size_t)p.x * 16 + o];
        float a = __uint_as_float(pair << 16);
        float b = __uint_as_float(pair & 0xffff0000u);
        acc += fmaf(v, b - a, a);
    }
    float val = -INFINITY;
    if (o < NC) {
        float inv = 1.0f / fmaxf((float)hist[n], 1.0f);
        val = acc * inv + r2[(size_t)n * NC + o];
    }
    float mx = val;
    #pragma unroll
    for (int off = 8; off > 0; off >>= 1) mx = fmaxf(mx, __shfl_xor(mx, off, 16));
    float ex = (o < NC) ? expf(val - mx) : 0.0f;
    float ssum = ex;
    #pragma unroll
    for (int off = 8; off > 0; off >>= 1) ssum += __shfl_xor(ssum, off, 16);
    if (o < NC) out[(size_t)n * NC + o] = val - mx - logf(ssum);
}

extern "C" void kernel_launch(void* const* d_in, const int* in_sizes, int n_in,
                              void* d_out, int out_size, void* d_ws, size_t ws_size,
                              hipStream_t stream) {
    const float* x     = (const float*)d_in[0];
    const int*   ei    = (const int*)d_in[1];     // [2,E] src row then dst row
    const float* ea    = (const float*)d_in[2];   // [E,1]
    const float* W1    = (const float*)d_in[3];   // [2,32,16]
    const float* root1 = (const float*)d_in[4];   // [32,16]
    const float* b1    = (const float*)d_in[5];   // [16]
    const float* W2    = (const float*)d_in[6];   // [2,16,10]
    const float* root2 = (const float*)d_in[7];   // [16,10]
    const float* b2    = (const float*)d_in[8];   // [10]
    float* out = (float*)d_out;

    // Workspace layout (4-byte units). es first for 8B alignment.
    char* wsb = (char*)d_ws;
    int2*         es     = (int2*)wsb;                                  // 1.6M * 8B
    unsigned int* y      = (unsigned int*)(wsb + (size_t)E_EDGES * 8);  // 1.6M * 4B
    float*        r1h    = (float*)(y + (size_t)N_NODES * 16);          // 1.6M * 4B
    unsigned int* z      = (unsigned int*)(r1h + (size_t)N_NODES * HID);// 1.6M * 4B
    float*        r2     = (float*)(z + (size_t)N_NODES * 16);          // 1.0M * 4B
    int*          hist   = (int*)(r2 + (size_t)N_NODES * NC);           // 100k (zeroed)
    int*          start  = hist + N_NODES;                              // 100k+1
    int*          cursor = start + N_NODES + 1;                         // 100k

    hipMemsetAsync(hist, 0, (size_t)N_NODES * sizeof(int), stream);

    int nodeGrid = (N_NODES + 255) / 256;
    int edgeGrid = (E_EDGES + 255) / 256;
    int aggGrid  = (N_NODES * 16 + 255) / 256;

    node_l1  <<<nodeGrid, 256, 0, stream>>>(x, W1, root1, b1, y, r1h);
    k_hist   <<<edgeGrid, 256, 0, stream>>>(ei, hist);
    k_scan   <<<1, SCAN_T, 0, stream>>>(hist, start, cursor);
    k_scatter<<<edgeGrid, 256, 0, stream>>>(ei, ea, cursor, es);
    k_agg1   <<<aggGrid, 256, 0, stream>>>(es, start, hist, y, r1h);
    node_proj2<<<nodeGrid, 256, 0, stream>>>(r1h, W2, root2, b2, z, r2);
    k_agg2   <<<aggGrid, 256, 0, stream>>>(es, start, hist, z, r2, out);
}

// Round 4
// 402.567 us; speedup vs baseline: 5.4375x; 1.5492x over previous
//
#include <hip/hip_runtime.h>
#include <math.h>

#define N_NODES 100000
#define E_EDGES 1600000
#define F_IN 32
#define HID 16
#define NC 10
#define SCAN_BLK 1024            // elements per scan block (256 threads * 4)
#define SCAN_NB ((N_NODES + SCAN_BLK - 1) / SCAN_BLK)   // 98

// bf16 pack (RNE) of two floats into one uint: low16 = lo, high16 = hi
__device__ __forceinline__ unsigned int bf16pair(float lo, float hi) {
    unsigned int ulo = __float_as_uint(lo), uhi = __float_as_uint(hi);
    ulo += 0x7fffu + ((ulo >> 16) & 1u);
    uhi += 0x7fffu + ((uhi >> 16) & 1u);
    return (ulo >> 16) | (uhi & 0xffff0000u);
}

// ---------------- Kernel: per-node projections for layer 1 ----------------
// y[n] = 16 uints, pair o = (x@W1[0])[o] , (x@W1[1])[o] in bf16. r1 = x@root1+b1 (f32).
__global__ __launch_bounds__(256) void node_l1(
    const float* __restrict__ x, const float* __restrict__ W1,
    const float* __restrict__ root1, const float* __restrict__ b1,
    unsigned int* __restrict__ y, float* __restrict__ r1)
{
    __shared__ float sW0[F_IN * HID], sW1[F_IN * HID], sR[F_IN * HID], sB[HID];
    for (int i = threadIdx.x; i < F_IN * HID; i += 256) {
        sW0[i] = W1[i];
        sW1[i] = W1[F_IN * HID + i];
        sR[i]  = root1[i];
    }
    if (threadIdx.x < HID) sB[threadIdx.x] = b1[threadIdx.x];
    __syncthreads();

    int n = blockIdx.x * 256 + threadIdx.x;
    if (n >= N_NODES) return;

    float xr[F_IN];
    const float4* xp = (const float4*)(x + (size_t)n * F_IN);
    #pragma unroll
    for (int i = 0; i < F_IN / 4; i++) {
        float4 t = xp[i];
        xr[i*4+0] = t.x; xr[i*4+1] = t.y; xr[i*4+2] = t.z; xr[i*4+3] = t.w;
    }

    float a0[HID], a1[HID], ar[HID];
    #pragma unroll
    for (int o = 0; o < HID; o++) { a0[o] = 0.f; a1[o] = 0.f; ar[o] = sB[o]; }
    for (int i = 0; i < F_IN; i++) {
        float xi = xr[i];
        #pragma unroll
        for (int o = 0; o < HID; o++) {
            a0[o] += xi * sW0[i * HID + o];
            a1[o] += xi * sW1[i * HID + o];
            ar[o] += xi * sR[i * HID + o];
        }
    }
    unsigned int* py = y + (size_t)n * 16;
    float* pr = r1 + (size_t)n * HID;
    #pragma unroll
    for (int o = 0; o < HID; o++) {
        py[o] = bf16pair(a0[o], a1[o]);
        pr[o] = ar[o];
    }
}

// ---------------- Sort step 1: histogram over dst (also = deg) ----------------
__global__ __launch_bounds__(256) void k_hist(const int* __restrict__ ei, int* __restrict__ hist)
{
    int e = blockIdx.x * 256 + threadIdx.x;
    if (e >= E_EDGES) return;
    atomicAdd(&hist[ei[E_EDGES + e]], 1);
}

// ---- Sort step 2a: per-block scan. Block b covers [b*1024, b*1024+1024). ----
// Writes within-block exclusive prefix into start[], block total into bsum[b].
__global__ __launch_bounds__(256) void scan_a(const int* __restrict__ hist,
                                              int* __restrict__ start,
                                              int* __restrict__ bsum)
{
    __shared__ int lds[256];
    int t = threadIdx.x;
    int base = blockIdx.x * SCAN_BLK + t * 4;
    int v0 = 0, v1 = 0, v2 = 0, v3 = 0;
    if (base + 3 < N_NODES) {
        int4 h4 = *(const int4*)(hist + base);
        v0 = h4.x; v1 = h4.y; v2 = h4.z; v3 = h4.w;
    } else {
        if (base + 0 < N_NODES) v0 = hist[base + 0];
        if (base + 1 < N_NODES) v1 = hist[base + 1];
        if (base + 2 < N_NODES) v2 = hist[base + 2];
        if (base + 3 < N_NODES) v3 = hist[base + 3];
    }
    int s = v0 + v1 + v2 + v3;
    lds[t] = s;
    __syncthreads();
    #pragma unroll
    for (int off = 1; off < 256; off <<= 1) {
        int u = (t >= off) ? lds[t - off] : 0;
        __syncthreads();
        lds[t] += u;
        __syncthreads();
    }
    int ex = lds[t] - s;   // exclusive prefix of this thread within block
    if (base + 0 < N_NODES) start[base + 0] = ex;
    if (base + 1 < N_NODES) start[base + 1] = ex + v0;
    if (base + 2 < N_NODES) start[base + 2] = ex + v0 + v1;
    if (base + 3 < N_NODES) start[base + 3] = ex + v0 + v1 + v2;
    if (t == 255) bsum[blockIdx.x] = lds[255];
}

// ---- Sort step 2b: scan the 98 block sums (single small block). ----
__global__ __launch_bounds__(128) void scan_b(const int* __restrict__ bsum,
                                              int* __restrict__ boff,
                                              int* __restrict__ start)
{
    __shared__ int lds[128];
    int t = threadIdx.x;
    int s = (t < SCAN_NB) ? bsum[t] : 0;
    lds[t] = s;
    __syncthreads();
    #pragma unroll
    for (int off = 1; off < 128; off <<= 1) {
        int u = (t >= off) ? lds[t - off] : 0;
        __syncthreads();
        lds[t] += u;
        __syncthreads();
    }
    if (t < SCAN_NB) boff[t] = lds[t] - s;
    if (t == 127) start[N_NODES] = lds[127];   // total = E
}

// ---- Sort step 2c: add block offsets; mirror into cursor. ----
__global__ __launch_bounds__(256) void scan_c(int* __restrict__ start,
                                              int* __restrict__ cursor,
                                              const int* __restrict__ boff)
{
    int t = threadIdx.x;
    int off = boff[blockIdx.x];
    int base = blockIdx.x * SCAN_BLK + t * 4;
    #pragma unroll
    for (int i = 0; i < 4; i++) {
        int j = base + i;
        if (j < N_NODES) {
            int v = start[j] + off;
            start[j] = v;
            cursor[j] = v;
        }
    }
}

// ---------------- Sort step 3: scatter (src, v) into dst-sorted order ----------------
__global__ __launch_bounds__(256) void k_scatter(const int* __restrict__ ei,
                                                 const float* __restrict__ ea,
                                                 int* __restrict__ cursor,
                                                 int2* __restrict__ es)
{
    int e = blockIdx.x * 256 + threadIdx.x;
    if (e >= E_EDGES) return;
    int dst = ei[E_EDGES + e];
    int pos = atomicAdd(&cursor[dst], 1);
    es[pos] = make_int2(ei[e], __float_as_int(ea[e]));
}

// ------- Aggregation layer 1: 16 lanes/node, atomic-free; fused mean+root+elu -------
// In-place: r1h holds r1 on entry, h on exit.
__global__ __launch_bounds__(256) void k_agg1(
    const int2* __restrict__ es, const int* __restrict__ start,
    const int* __restrict__ hist, const unsigned int* __restrict__ y,
    float* __restrict__ r1h)
{
    int idx = blockIdx.x * 256 + threadIdx.x;
    int n = idx >> 4, o = idx & 15;
    if (n >= N_NODES) return;
    int j0 = start[n], j1 = start[n + 1];
    float acc = 0.f;
    for (int j = j0; j < j1; j++) {
        int2 p = es[j];
        float v = __int_as_float(p.y);
        unsigned int pair = y[(size_t)p.x * 16 + o];   // one 64B line per edge (16 lanes x 4B)
        float a = __uint_as_float(pair << 16);
        float b = __uint_as_float(pair & 0xffff0000u);
        acc += fmaf(v, b - a, a);                      // a*(1-v) + b*v
    }
    float inv = 1.0f / fmaxf((float)hist[n], 1.0f);
    float hv = acc * inv + r1h[(size_t)n * HID + o];
    r1h[(size_t)n * HID + o] = hv > 0.0f ? hv : expm1f(hv);  // elu
}

// ---------------- Layer-2 projections: z (bf16 pairs, padded), r2 ----------------
__global__ __launch_bounds__(256) void node_proj2(
    const float* __restrict__ h,
    const float* __restrict__ W2, const float* __restrict__ root2,
    const float* __restrict__ b2,
    unsigned int* __restrict__ z, float* __restrict__ r2)
{
    __shared__ float sW0[HID * NC], sW1[HID * NC], sR[HID * NC], sB[NC];
    for (int i = threadIdx.x; i < HID * NC; i += 256) {
        sW0[i] = W2[i];
        sW1[i] = W2[HID * NC + i];
        sR[i]  = root2[i];
    }
    if (threadIdx.x < NC) sB[threadIdx.x] = b2[threadIdx.x];
    __syncthreads();

    int n = blockIdx.x * 256 + threadIdx.x;
    if (n >= N_NODES) return;

    float hr[HID];
    const float4* hp = (const float4*)(h + (size_t)n * HID);
    #pragma unroll
    for (int i = 0; i < HID / 4; i++) {
        float4 t = hp[i];
        hr[i*4+0] = t.x; hr[i*4+1] = t.y; hr[i*4+2] = t.z; hr[i*4+3] = t.w;
    }
    float a0[NC], a1[NC], ar[NC];
    #pragma unroll
    for (int c = 0; c < NC; c++) { a0[c] = 0.f; a1[c] = 0.f; ar[c] = sB[c]; }
    for (int i = 0; i < HID; i++) {
        float hi = hr[i];
        #pragma unroll
        for (int c = 0; c < NC; c++) {
            a0[c] += hi * sW0[i * NC + c];
            a1[c] += hi * sW1[i * NC + c];
            ar[c] += hi * sR[i * NC + c];
        }
    }
    unsigned int* pz = z + (size_t)n * 16;
    float* pr = r2 + (size_t)n * NC;
    #pragma unroll
    for (int c = 0; c < NC; c++) {
        pz[c] = bf16pair(a0[c], a1[c]);
        pr[c] = ar[c];
    }
    #pragma unroll
    for (int c = NC; c < 16; c++) pz[c] = 0u;   // keep lanes 10..15 benign
}

// -- Aggregation layer 2: 16 lanes/node; fused mean+root+log_softmax (shfl, width 16) --
__global__ __launch_bounds__(256) void k_agg2(
    const int2* __restrict__ es, const int* __restrict__ start,
    const int* __restrict__ hist, const unsigned int* __restrict__ z,
    const float* __restrict__ r2, float* __restrict__ out)
{
    int idx = blockIdx.x * 256 + threadIdx.x;
    int n = idx >> 4, o = idx & 15;
    if (n >= N_NODES) return;
    int j0 = start[n], j1 = start[n + 1];
    float acc = 0.f;
    for (int j = j0; j < j1; j++) {
        int2 p = es[j];
        float v = __int_as_float(p.y);
        unsigned int pair = z[(size_t)p.x * 16 + o];
        float a = __uint_as_float(pair << 16);
        float b = __uint_as_float(pair & 0xffff0000u);
        acc += fmaf(v, b - a, a);
    }
    float val = -INFINITY;
    if (o < NC) {
        float inv = 1.0f / fmaxf((float)hist[n], 1.0f);
        val = acc * inv + r2[(size_t)n * NC + o];
    }
    float mx = val;
    #pragma unroll
    for (int off = 8; off > 0; off >>= 1) mx = fmaxf(mx, __shfl_xor(mx, off, 16));
    float ex = (o < NC) ? expf(val - mx) : 0.0f;
    float ssum = ex;
    #pragma unroll
    for (int off = 8; off > 0; off >>= 1) ssum += __shfl_xor(ssum, off, 16);
    if (o < NC) out[(size_t)n * NC + o] = val - mx - logf(ssum);
}

extern "C" void kernel_launch(void* const* d_in, const int* in_sizes, int n_in,
                              void* d_out, int out_size, void* d_ws, size_t ws_size,
                              hipStream_t stream) {
    const float* x     = (const float*)d_in[0];
    const int*   ei    = (const int*)d_in[1];     // [2,E] src row then dst row
    const float* ea    = (const float*)d_in[2];   // [E,1]
    const float* W1    = (const float*)d_in[3];   // [2,32,16]
    const float* root1 = (const float*)d_in[4];   // [32,16]
    const float* b1    = (const float*)d_in[5];   // [16]
    const float* W2    = (const float*)d_in[6];   // [2,16,10]
    const float* root2 = (const float*)d_in[7];   // [16,10]
    const float* b2    = (const float*)d_in[8];   // [10]
    float* out = (float*)d_out;

    // Workspace layout (4-byte units). es first for 16B alignment of later arrays.
    char* wsb = (char*)d_ws;
    int2*         es     = (int2*)wsb;                                  // 1.6M * 8B
    unsigned int* y      = (unsigned int*)(wsb + (size_t)E_EDGES * 8);  // 1.6M * 4B
    float*        r1h    = (float*)(y + (size_t)N_NODES * 16);          // 1.6M * 4B
    unsigned int* z      = (unsigned int*)(r1h + (size_t)N_NODES * HID);// 1.6M * 4B
    float*        r2     = (float*)(z + (size_t)N_NODES * 16);          // 1.0M * 4B
    int*          hist   = (int*)(r2 + (size_t)N_NODES * NC);           // 100k (zeroed)
    int*          start  = hist + N_NODES;                              // 100k+1
    int*          cursor = start + N_NODES + 1;                         // 100k
    int*          bsum   = cursor + N_NODES;                            // 98
    int*          boff   = bsum + SCAN_NB;                              // 98

    hipMemsetAsync(hist, 0, (size_t)N_NODES * sizeof(int), stream);

    int nodeGrid = (N_NODES + 255) / 256;
    int edgeGrid = (E_EDGES + 255) / 256;
    int aggGrid  = (N_NODES * 16 + 255) / 256;

    node_l1  <<<nodeGrid, 256, 0, stream>>>(x, W1, root1, b1, y, r1h);
    k_hist   <<<edgeGrid, 256, 0, stream>>>(ei, hist);
    scan_a   <<<SCAN_NB, 256, 0, stream>>>(hist, start, bsum);
    scan_b   <<<1, 128, 0, stream>>>(bsum, boff, start);
    scan_c   <<<SCAN_NB, 256, 0, stream>>>(start, cursor, boff);
    k_scatter<<<edgeGrid, 256, 0, stream>>>(ei, ea, cursor, es);
    k_agg1   <<<aggGrid, 256, 0, stream>>>(es, start, hist, y, r1h);
    node_proj2<<<nodeGrid, 256, 0, stream>>>(r1h, W2, root2, b2, z, r2);
    k_agg2   <<<aggGrid, 256, 0, stream>>>(es, start, hist, z, r2, out);
}